// Round 1
// 1427.657 us; speedup vs baseline: 1.2040x; 1.2040x over previous
//
#include <hip/hip_runtime.h>
#include <stdint.h>

#define T_STEPS 128
#define BATCH   512
#define OBSD    1024
#define HD      512
#define FCD     512
#define MROWS   (T_STEPS * BATCH)   // 65536

typedef unsigned short ushort_t;
typedef __attribute__((ext_vector_type(8))) short bf16x8;
typedef __attribute__((ext_vector_type(4))) float f32x4;
typedef __attribute__((ext_vector_type(2))) uint32_t u32x2;

__device__ inline ushort_t f2bf(float f) {
    union { float f; uint32_t u; } v; v.f = f;
    uint32_t r = v.u + 0x7FFFu + ((v.u >> 16) & 1u);
    return (ushort_t)(r >> 16);
}
__device__ inline float bf2f(ushort_t h) {
    union { uint32_t u; float f; } v; v.u = ((uint32_t)h) << 16;
    return v.f;
}
__device__ inline float fsigmoid(float x) {
    x = fminf(fmaxf(x, -30.f), 30.f);
    return 1.f / (1.f + __expf(-x));
}
__device__ inline float ftanh(float x) {
    float e = __expf(fminf(fmaxf(2.f * x, -30.f), 30.f));
    return (e - 1.f) / (e + 1.f);
}
// packed f32->bf16 (RNE), 1 VALU op per 2 elements
__device__ inline uint32_t cvt_pk_bf16(float lo, float hi) {
    uint32_t r;
    asm("v_cvt_pk_bf16_f32 %0, %1, %2" : "=v"(r) : "v"(lo), "v"(hi));
    return r;
}
// async global->LDS, 16B per lane; dest must be wave-uniform base + lane*16
__device__ inline void gload16(const void* g, void* l) {
    __builtin_amdgcn_global_load_lds(
        (const __attribute__((address_space(1))) uint32_t*)g,
        (__attribute__((address_space(3))) uint32_t*)l, 16, 0, 0);
}

// ---------------- weight prep: fp32 [R,C] -> bf16 [C,R] ----------------
__global__ void transpose_to_bf16(const float* __restrict__ in,
                                  ushort_t* __restrict__ out, int R, int C) {
    __shared__ float tile[32][33];
    int tx = threadIdx.x, ty = threadIdx.y;
    int c0 = blockIdx.x * 32, r0 = blockIdx.y * 32;
    for (int yy = 0; yy < 4; ++yy)
        tile[ty + 8 * yy][tx] = in[(size_t)(r0 + ty + 8 * yy) * C + c0 + tx];
    __syncthreads();
    for (int yy = 0; yy < 4; ++yy)
        out[(size_t)(c0 + ty + 8 * yy) * R + r0 + tx] = f2bf(tile[tx][ty + 8 * yy]);
}

// init: value <- bc2, barrier counters <- 0
__global__ void init_misc(float* __restrict__ v, const float* __restrict__ bc2,
                          unsigned* __restrict__ bar) {
    int i = blockIdx.x * blockDim.x + threadIdx.x;
    if (i < MROWS) v[i] = bc2[0];
    if (i < 2048) bar[i] = 0u;
}

// ---------------- 128x128 MFMA GEMM (m97 structure): C = A @ B ----------
// 4 waves in 2x2, each wave owns a 64x64 quadrant = 4x4 16x16x32 frags.
// B (and bf16 A) staged via global_load_lds dwordx4 into linear LDS.
// fp32 A (gemm1) reg-staged with v_cvt_pk_bf16_f32.
// Launch grid = (Ntiles, Mtiles): N innermost so blocks sharing an A-row
// panel are concurrent -> A fetched from HBM once, re-served by L3.
template <int K, int EPI, bool AF32>
__global__ __launch_bounds__(256, 2) void gemm128(
    const void* __restrict__ Aptr, const ushort_t* __restrict__ BT,
    const float* __restrict__ bias, ushort_t* __restrict__ Cout, int ldc,
    const float* __restrict__ wc2, float* __restrict__ value) {
    __shared__ __align__(16) ushort_t Als[128][32];   // 8 KB, linear
    __shared__ __align__(16) ushort_t Bls[128][32];   // 8 KB, linear
    int tid = threadIdx.x;
    int wave = tid >> 6, lane = tid & 63, quad = lane >> 4, l16 = lane & 15;
    int wr = wave >> 1, wc = wave & 1;
    int bm = blockIdx.y * 128, bn = blockIdx.x * 128;

    f32x4 acc[4][4];
#pragma unroll
    for (int m = 0; m < 4; ++m)
#pragma unroll
        for (int n = 0; n < 4; ++n) acc[m][n] = (f32x4){0.f, 0.f, 0.f, 0.f};

    int srow = tid >> 2;            // 0..63: staged row within half-tile
    int sk = (tid & 3) * 8;         // k-element chunk (8 bf16 = 16 B)
    const ushort_t* Bt0 = &BT[(size_t)(bn + srow) * K + sk];
    const ushort_t* Bt1 = &BT[(size_t)(bn + 64 + srow) * K + sk];
    char* AlsDst = (char*)&Als[0][0] + tid * 16;
    char* BlsDst = (char*)&Bls[0][0] + tid * 16;
    const ushort_t* At0 = nullptr;
    const ushort_t* At1 = nullptr;
    if constexpr (!AF32) {
        const ushort_t* A = (const ushort_t*)Aptr;
        At0 = &A[(size_t)(bm + srow) * K + sk];
        At1 = &A[(size_t)(bm + 64 + srow) * K + sk];
    }

#pragma unroll 1
    for (int k0 = 0; k0 < K; k0 += 32) {
        if constexpr (AF32) {
            const float* A = (const float*)Aptr;
#pragma unroll
            for (int j = 0; j < 4; ++j) {
                int f = tid + 256 * j;          // float4 id in [128][32] tile
                int r = f >> 3, c4 = f & 7;
                float4 av =
                    *(const float4*)&A[(size_t)(bm + r) * K + k0 + c4 * 4];
                u32x2 w;
                w[0] = cvt_pk_bf16(av.x, av.y);
                w[1] = cvt_pk_bf16(av.z, av.w);
                *(u32x2*)&Als[r][c4 * 4] = w;
            }
        } else {
            gload16(At0 + k0, AlsDst);
            gload16(At1 + k0, AlsDst + 4096);
        }
        gload16(Bt0 + k0, BlsDst);
        gload16(Bt1 + k0, BlsDst + 4096);
        __syncthreads();   // waits vmcnt(0): global_load_lds done

        bf16x8 af[4], bfr[4];
#pragma unroll
        for (int m = 0; m < 4; ++m)
            af[m] = *(const bf16x8*)&Als[wr * 64 + m * 16 + l16][quad * 8];
#pragma unroll
        for (int n = 0; n < 4; ++n)
            bfr[n] = *(const bf16x8*)&Bls[wc * 64 + n * 16 + l16][quad * 8];
#pragma unroll
        for (int m = 0; m < 4; ++m)
#pragma unroll
            for (int n = 0; n < 4; ++n)
                acc[m][n] = __builtin_amdgcn_mfma_f32_16x16x32_bf16(
                    af[m], bfr[n], acc[m][n], 0, 0, 0);
        __syncthreads();
    }

    // C/D frag mapping: col = l16, row = quad*4 + i
    int rbase = bm + wr * 64 + quad * 4;
    if constexpr (EPI == 0 || EPI == 1) {
#pragma unroll
        for (int n = 0; n < 4; ++n) {
            int col = bn + wc * 64 + n * 16 + l16;
            float bv = bias[col];
#pragma unroll
            for (int m = 0; m < 4; ++m) {
#pragma unroll
                for (int i = 0; i < 4; ++i) {
                    float v = acc[m][n][i] + bv;
                    if constexpr (EPI == 0) v = fmaxf(v, 0.f);
                    Cout[(size_t)(rbase + m * 16 + i) * ldc + col] = f2bf(v);
                }
            }
        }
    } else {
        float s[4][4];
#pragma unroll
        for (int m = 0; m < 4; ++m)
#pragma unroll
            for (int i = 0; i < 4; ++i) s[m][i] = 0.f;
#pragma unroll
        for (int n = 0; n < 4; ++n) {
            int col = bn + wc * 64 + n * 16 + l16;
            float bv = bias[col], w2 = wc2[col];
#pragma unroll
            for (int m = 0; m < 4; ++m)
#pragma unroll
                for (int i = 0; i < 4; ++i)
                    s[m][i] += fmaxf(acc[m][n][i] + bv, 0.f) * w2;
        }
#pragma unroll
        for (int m = 0; m < 4; ++m)
#pragma unroll
            for (int i = 0; i < 4; ++i) {
                float v = s[m][i];
                v += __shfl_xor(v, 1);
                v += __shfl_xor(v, 2);
                v += __shfl_xor(v, 4);
                v += __shfl_xor(v, 8);
                if (l16 == 0) atomicAdd(&value[rbase + m * 16 + i], v);
            }
    }
}

// ---------------- rowwise LayerNorm over H=512, in-place on bf16 --------
__global__ __launch_bounds__(256) void ln_kernel(ushort_t* __restrict__ emb,
                                                 const float* __restrict__ scale,
                                                 const float* __restrict__ biasv) {
    int wave = threadIdx.x >> 6, lane = threadIdx.x & 63;
    size_t row = (size_t)blockIdx.x * 4 + wave;
    ushort_t* p = &emb[row * HD + lane * 8];
    bf16x8 xv = *(const bf16x8*)p;
    float x[8];
    float sum = 0.f, sq = 0.f;
    for (int j = 0; j < 8; ++j) {
        x[j] = bf2f((ushort_t)xv[j]);
        sum += x[j];
        sq += x[j] * x[j];
    }
    for (int off = 32; off > 0; off >>= 1) {
        sum += __shfl_xor(sum, off);
        sq += __shfl_xor(sq, off);
    }
    float mean = sum * (1.f / 512.f);
    float var = fmaxf(sq * (1.f / 512.f) - mean * mean, 0.f);
    float inv = rsqrtf(var + 1e-6f);
    bf16x8 ov;
    for (int j = 0; j < 8; ++j) {
        int col = lane * 8 + j;
        ov[j] = (short)f2bf((x[j] - mean) * inv * scale[col] + biasv[col]);
    }
    *(bf16x8*)p = ov;
}

// ---------------- GRU scan: persistent 256 blocks, LDS Wh, fence-free ---
// bg = bid&7 (XCD-local groups under bid%8 heuristic — perf only, not
// correctness), cg = bid>>3. Block owns rows [bg*64,+64) x cols [cg*16,+16).
// Wh slice in LDS. h ping-pong via sc0+sc1 (agent-coherent, L2-bypass)
// loads/stores. a-frags: ONE asm block of 16 global_load_dwordx4 sc0 sc1
// + s_waitcnt inside — compiler cannot serialize; 1 L3 latency total.
__global__ __launch_bounds__(256, 1) void scan_coop(
    const float* __restrict__ hidden, const int* __restrict__ dones,
    const ushort_t* __restrict__ WhT, const float* __restrict__ bhn,
    const ushort_t* __restrict__ xproj, ushort_t* __restrict__ ys,
    float* __restrict__ hlast, ushort_t* hb0, ushort_t* hb1,
    unsigned* bar) {
    __shared__ __align__(16) ushort_t Wls[48][520];   // 49,920 B
    int tid = threadIdx.x;
    int wave = tid >> 6, lane = tid & 63, quad = lane >> 4, l16 = lane & 15;
    int bid = blockIdx.x;
    int bg = bid & 7, cg = bid >> 3;
    int row0 = bg * 64 + wave * 16;   // this wave's 16 batch rows
    int col0 = cg * 16;               // this block's 16 h-cols

    // ---- stage Wh slice into LDS: row c = gate(c>>4), local col (c&15) ----
    for (int idx = tid; idx < 48 * 64; idx += 256) {
        int c = idx >> 6, ck = (idx & 63) * 8;
        int g = c >> 4, lc = c & 15;
        *(bf16x8*)&Wls[c][ck] =
            *(const bf16x8*)&WhT[(size_t)(g * 512 + col0 + lc) * 512 + ck];
    }

    // ---- fp32 master h (C-layout: col=l16, row=quad*4+i), done(0)-masked --
    float mast[4];
    int rbase = row0 + quad * 4;
#pragma unroll
    for (int i = 0; i < 4; ++i) {
        float h0 = hidden[(size_t)(rbase + i) * HD + col0 + l16];
        mast[i] = dones[rbase + i] ? 0.f : h0;   // dones[0*BATCH + r]
    }
    float bhnv = bhn[col0 + l16];

    unsigned* cnt = &bar[bg * 256];   // 8 sub-counters, 128 B apart
    unsigned* mycnt = &cnt[(cg & 7) * 32];

    // ---- publish(0) into hb0 ----
#pragma unroll
    for (int i = 0; i < 4; ++i) {
        unsigned u = f2bf(mast[i]);
        unsigned p1 = __shfl_xor((int)u, 1);
        unsigned u32 = u | (p1 << 16);
        unsigned hi = __shfl_xor((int)u32, 2);
        if ((l16 & 3) == 0) {
            unsigned long long q =
                (unsigned long long)u32 | ((unsigned long long)hi << 32);
            __hip_atomic_store(
                (unsigned long long*)&hb0[(size_t)(rbase + i) * HD + col0 + l16],
                q, __ATOMIC_RELAXED, __HIP_MEMORY_SCOPE_AGENT);
        }
    }
    // prefetch xproj(0) and dones(1)
    float xr[4], xz[4], xn[4];
    int dn_nxt[4];
#pragma unroll
    for (int i = 0; i < 4; ++i) {
        size_t m = (size_t)(rbase + i);
        const ushort_t* xp = &xproj[m * 1536 + col0 + l16];
        xr[i] = bf2f(xp[0]);
        xz[i] = bf2f(xp[512]);
        xn[i] = bf2f(xp[1024]);
        dn_nxt[i] = dones[BATCH + rbase + i];
    }
    __builtin_amdgcn_s_waitcnt(0);   // publishes acked at coherent pt; LDS done
    __syncthreads();
    if (tid == 0)
        __hip_atomic_fetch_add(mycnt, 1u, __ATOMIC_RELAXED,
                               __HIP_MEMORY_SCOPE_AGENT);

    for (int t = 0; t < T_STEPS; ++t) {
        // ---- barrier wait: all 32 group blocks published step t ----
        if (tid == 0) {
            unsigned target = 32u * (unsigned)(t + 1);
            for (;;) {
                unsigned s = 0;
#pragma unroll
                for (int c = 0; c < 8; ++c)
                    s += __hip_atomic_load(&cnt[c * 32], __ATOMIC_RELAXED,
                                           __HIP_MEMORY_SCOPE_AGENT);
                if (s >= target) break;
                __builtin_amdgcn_s_sleep(1);
            }
        }
        __syncthreads();
        asm volatile("" ::: "memory");
        ushort_t* rbuf = (t & 1) ? hb1 : hb0;
        ushort_t* wnext = (t & 1) ? hb0 : hb1;

        // ---- a-frags: one asm batch, 16 independent 16B sc0+sc1 loads,
        //      single waitcnt inside the block (no compiler serialization)
        bf16x8 afr[16];
        {
            const ushort_t* ap =
                &rbuf[(size_t)(row0 + l16) * HD + quad * 8];
            asm volatile(
                "global_load_dwordx4 %0, %16, off sc0 sc1\n\t"
                "global_load_dwordx4 %1, %16, off offset:64 sc0 sc1\n\t"
                "global_load_dwordx4 %2, %16, off offset:128 sc0 sc1\n\t"
                "global_load_dwordx4 %3, %16, off offset:192 sc0 sc1\n\t"
                "global_load_dwordx4 %4, %16, off offset:256 sc0 sc1\n\t"
                "global_load_dwordx4 %5, %16, off offset:320 sc0 sc1\n\t"
                "global_load_dwordx4 %6, %16, off offset:384 sc0 sc1\n\t"
                "global_load_dwordx4 %7, %16, off offset:448 sc0 sc1\n\t"
                "global_load_dwordx4 %8, %16, off offset:512 sc0 sc1\n\t"
                "global_load_dwordx4 %9, %16, off offset:576 sc0 sc1\n\t"
                "global_load_dwordx4 %10, %16, off offset:640 sc0 sc1\n\t"
                "global_load_dwordx4 %11, %16, off offset:704 sc0 sc1\n\t"
                "global_load_dwordx4 %12, %16, off offset:768 sc0 sc1\n\t"
                "global_load_dwordx4 %13, %16, off offset:832 sc0 sc1\n\t"
                "global_load_dwordx4 %14, %16, off offset:896 sc0 sc1\n\t"
                "global_load_dwordx4 %15, %16, off offset:960 sc0 sc1\n\t"
                "s_waitcnt vmcnt(0)"
                : "=&v"(afr[0]), "=&v"(afr[1]), "=&v"(afr[2]), "=&v"(afr[3]),
                  "=&v"(afr[4]), "=&v"(afr[5]), "=&v"(afr[6]), "=&v"(afr[7]),
                  "=&v"(afr[8]), "=&v"(afr[9]), "=&v"(afr[10]), "=&v"(afr[11]),
                  "=&v"(afr[12]), "=&v"(afr[13]), "=&v"(afr[14]), "=&v"(afr[15])
                : "v"(ap)
                : "memory");
        }
        f32x4 aR = (f32x4){0.f, 0.f, 0.f, 0.f};
        f32x4 aZ = (f32x4){0.f, 0.f, 0.f, 0.f};
        f32x4 aN = (f32x4){0.f, 0.f, 0.f, 0.f};
#pragma unroll
        for (int kt = 0; kt < 16; ++kt) {
            bf16x8 bR = *(const bf16x8*)&Wls[l16][kt * 32 + quad * 8];
            bf16x8 bZ = *(const bf16x8*)&Wls[16 + l16][kt * 32 + quad * 8];
            bf16x8 bN = *(const bf16x8*)&Wls[32 + l16][kt * 32 + quad * 8];
            aR = __builtin_amdgcn_mfma_f32_16x16x32_bf16(afr[kt], bR, aR, 0, 0, 0);
            aZ = __builtin_amdgcn_mfma_f32_16x16x32_bf16(afr[kt], bZ, aZ, 0, 0, 0);
            aN = __builtin_amdgcn_mfma_f32_16x16x32_bf16(afr[kt], bN, aN, 0, 0, 0);
        }

        // ---- gates; pack hnew 4 lanes->8B once, reuse for publish & ys ----
        unsigned long long qpk[4];
        float hnew[4];
#pragma unroll
        for (int i = 0; i < 4; ++i) {
            float r = fsigmoid(xr[i] + aR[i]);
            float z = fsigmoid(xz[i] + aZ[i]);
            float n = ftanh(xn[i] + r * (aN[i] + bhnv));
            hnew[i] = (1.f - z) * n + z * mast[i];
            unsigned u = f2bf(hnew[i]);
            unsigned p1 = __shfl_xor((int)u, 1);
            unsigned u32 = u | (p1 << 16);
            unsigned hi = __shfl_xor((int)u32, 2);
            qpk[i] = (unsigned long long)u32 | ((unsigned long long)hi << 32);
            mast[i] = (t < T_STEPS - 1 && dn_nxt[i]) ? 0.f : hnew[i];
        }
        if (t < T_STEPS - 1 && (l16 & 3) == 0) {
#pragma unroll
            for (int i = 0; i < 4; ++i) {
                unsigned long long qp = dn_nxt[i] ? 0ull : qpk[i];
                __hip_atomic_store(
                    (unsigned long long*)&wnext[(size_t)(rbase + i) * HD +
                                                col0 + l16],
                    qp, __ATOMIC_RELAXED, __HIP_MEMORY_SCOPE_AGENT);
            }
        }
        asm volatile("" ::: "memory");
        __builtin_amdgcn_s_waitcnt(0);   // drain publishes
        // ---- ys stores (packed 8B) + next-step prefetch: overlap poll ----
        if ((l16 & 3) == 0) {
#pragma unroll
            for (int i = 0; i < 4; ++i) {
                size_t m = (size_t)t * BATCH + rbase + i;
                *(unsigned long long*)&ys[m * HD + col0 + l16] = qpk[i];
            }
        }
        if (t < T_STEPS - 1) {
            int tn = t + 1;
            int td = (t + 2 < T_STEPS) ? t + 2 : T_STEPS - 1;
#pragma unroll
            for (int i = 0; i < 4; ++i) {
                size_t m = (size_t)tn * BATCH + rbase + i;
                const ushort_t* xp = &xproj[m * 1536 + col0 + l16];
                xr[i] = bf2f(xp[0]);
                xz[i] = bf2f(xp[512]);
                xn[i] = bf2f(xp[1024]);
                dn_nxt[i] = dones[td * BATCH + rbase + i];
            }
        }
        asm volatile("" ::: "memory");   // pin prefetch above arrive/poll
        __syncthreads();
        if (tid == 0 && t < T_STEPS - 1)
            __hip_atomic_fetch_add(mycnt, 1u, __ATOMIC_RELAXED,
                                   __HIP_MEMORY_SCOPE_AGENT);
    }
#pragma unroll
    for (int i = 0; i < 4; ++i)
        hlast[(size_t)(rbase + i) * HD + col0 + l16] = mast[i];
}

extern "C" void kernel_launch(void* const* d_in, const int* in_sizes, int n_in,
                              void* d_out, int out_size, void* d_ws,
                              size_t ws_size, hipStream_t stream) {
    const float* hidden      = (const float*)d_in[0];
    const float* world_state = (const float*)d_in[1];
    const int*   dones       = (const int*)d_in[2];
    const float* Wd  = (const float*)d_in[3];
    const float* bd  = (const float*)d_in[4];
    const float* lns = (const float*)d_in[5];
    const float* lnb = (const float*)d_in[6];
    const float* Wi  = (const float*)d_in[7];
    const float* bi  = (const float*)d_in[8];
    const float* Wh  = (const float*)d_in[9];
    const float* bhn = (const float*)d_in[10];
    const float* Wc1 = (const float*)d_in[11];
    const float* bc1 = (const float*)d_in[12];
    const float* Wc2 = (const float*)d_in[13];
    const float* bc2 = (const float*)d_in[14];

    float* out_h = (float*)d_out;            // h_last [512,512]
    float* out_v = out_h + BATCH * HD;       // value  [128,512]

    char* ws = (char*)d_ws;
    ushort_t* WdT   = (ushort_t*)(ws + 0);            // [512][1024]
    ushort_t* WiT   = (ushort_t*)(ws + 1048576);      // [1536][512]
    ushort_t* WhT   = (ushort_t*)(ws + 2621440);      // [1536][512]
    ushort_t* Wc1T  = (ushort_t*)(ws + 4194304);      // [512][512]
    unsigned* bar   = (unsigned*)(ws + 4718592);      // 2048 uints (8 KB)
    ushort_t* hb0   = (ushort_t*)(ws + 4726784);      // [512][512] bf16
    ushort_t* hb1   = (ushort_t*)(ws + 5251072);      // [512][512] bf16
    ushort_t* xproj = (ushort_t*)(ws + 8388608);      // [65536][1536] bf16
    ushort_t* emb   = (ushort_t*)(ws + 209715200);    // [65536][512] bf16
    ushort_t* ysb   = emb;  // reuse: emb dead after gemm2, ys written by scan

    dim3 tb(32, 8);
    transpose_to_bf16<<<dim3(16, 32), tb, 0, stream>>>(Wd, WdT, OBSD, HD);
    transpose_to_bf16<<<dim3(48, 16), tb, 0, stream>>>(Wi, WiT, HD, 1536);
    transpose_to_bf16<<<dim3(48, 16), tb, 0, stream>>>(Wh, WhT, HD, 1536);
    transpose_to_bf16<<<dim3(16, 16), tb, 0, stream>>>(Wc1, Wc1T, HD, FCD);
    init_misc<<<256, 256, 0, stream>>>(out_v, bc2, bar);

    // emb = relu(world_state @ Wd + bd)   (fp32 A reg-staged w/ cvt_pk)
    gemm128<OBSD, 0, true><<<dim3(HD / 128, MROWS / 128), 256, 0, stream>>>(
        world_state, WdT, bd, emb, HD, nullptr, nullptr);
    // LayerNorm in place
    ln_kernel<<<MROWS / 4, 256, 0, stream>>>(emb, lns, lnb);
    // xproj = emb @ Wi + bi
    gemm128<HD, 1, false><<<dim3(1536 / 128, MROWS / 128), 256, 0, stream>>>(
        emb, WiT, bi, xproj, 1536, nullptr, nullptr);
    // persistent GRU scan: 256 blocks, bg=bid&7 XCD-local groups, LDS Wh,
    // batched-asm a-frag loads (1 L3 latency/step)
    scan_coop<<<dim3(256), dim3(256), 0, stream>>>(
        hidden, dones, WhT, bhn, xproj, ysb, out_h, hb0, hb1, bar);
    // value = relu(ys @ Wc1 + bc1) @ Wc2 + bc2
    gemm128<HD, 2, false><<<dim3(FCD / 128, MROWS / 128), 256, 0, stream>>>(
        ysb, Wc1T, bc1, nullptr, 0, Wc2, out_v);
}

// Round 2
// 1415.047 us; speedup vs baseline: 1.2147x; 1.0089x over previous
//
#include <hip/hip_runtime.h>
#include <stdint.h>

#define T_STEPS 128
#define BATCH   512
#define OBSD    1024
#define HD      512
#define FCD     512
#define MROWS   (T_STEPS * BATCH)   // 65536

typedef unsigned short ushort_t;
typedef __attribute__((ext_vector_type(8))) short bf16x8;
typedef __attribute__((ext_vector_type(4))) float f32x4;
typedef __attribute__((ext_vector_type(2))) uint32_t u32x2;

__device__ inline ushort_t f2bf(float f) {
    union { float f; uint32_t u; } v; v.f = f;
    uint32_t r = v.u + 0x7FFFu + ((v.u >> 16) & 1u);
    return (ushort_t)(r >> 16);
}
__device__ inline float bf2f(ushort_t h) {
    union { uint32_t u; float f; } v; v.u = ((uint32_t)h) << 16;
    return v.f;
}
__device__ inline float fsigmoid(float x) {
    x = fminf(fmaxf(x, -30.f), 30.f);
    return 1.f / (1.f + __expf(-x));
}
__device__ inline float ftanh(float x) {
    float e = __expf(fminf(fmaxf(2.f * x, -30.f), 30.f));
    return (e - 1.f) / (e + 1.f);
}
// packed f32->bf16 (RNE), 1 VALU op per 2 elements
__device__ inline uint32_t cvt_pk_bf16(float lo, float hi) {
    uint32_t r;
    asm("v_cvt_pk_bf16_f32 %0, %1, %2" : "=v"(r) : "v"(lo), "v"(hi));
    return r;
}
// async global->LDS, 16B per lane; dest must be wave-uniform base + lane*16
__device__ inline void gload16(const void* g, void* l) {
    __builtin_amdgcn_global_load_lds(
        (const __attribute__((address_space(1))) uint32_t*)g,
        (__attribute__((address_space(3))) uint32_t*)l, 16, 0, 0);
}

// ---------------- weight prep: fp32 [R,C] -> bf16 [C,R] ----------------
__global__ void transpose_to_bf16(const float* __restrict__ in,
                                  ushort_t* __restrict__ out, int R, int C) {
    __shared__ float tile[32][33];
    int tx = threadIdx.x, ty = threadIdx.y;
    int c0 = blockIdx.x * 32, r0 = blockIdx.y * 32;
    for (int yy = 0; yy < 4; ++yy)
        tile[ty + 8 * yy][tx] = in[(size_t)(r0 + ty + 8 * yy) * C + c0 + tx];
    __syncthreads();
    for (int yy = 0; yy < 4; ++yy)
        out[(size_t)(c0 + ty + 8 * yy) * R + r0 + tx] = f2bf(tile[tx][ty + 8 * yy]);
}

// init: value <- bc2, barrier flags <- 0
__global__ void init_misc(float* __restrict__ v, const float* __restrict__ bc2,
                          unsigned* __restrict__ bar) {
    int i = blockIdx.x * blockDim.x + threadIdx.x;
    if (i < MROWS) v[i] = bc2[0];
    if (i < 2048) bar[i] = 0u;
}

// ---------------- 128x128 MFMA GEMM (m97 structure): C = A @ B ----------
// 4 waves in 2x2, each wave owns a 64x64 quadrant = 4x4 16x16x32 frags.
// B (and bf16 A) staged via global_load_lds dwordx4 into linear LDS.
// fp32 A (gemm1) reg-staged with v_cvt_pk_bf16_f32.
// Launch grid = (Ntiles, Mtiles): N innermost so blocks sharing an A-row
// panel are concurrent -> A fetched from HBM once, re-served by L3.
template <int K, int EPI, bool AF32>
__global__ __launch_bounds__(256, 2) void gemm128(
    const void* __restrict__ Aptr, const ushort_t* __restrict__ BT,
    const float* __restrict__ bias, ushort_t* __restrict__ Cout, int ldc,
    const float* __restrict__ wc2, float* __restrict__ value) {
    __shared__ __align__(16) ushort_t Als[128][32];   // 8 KB, linear
    __shared__ __align__(16) ushort_t Bls[128][32];   // 8 KB, linear
    int tid = threadIdx.x;
    int wave = tid >> 6, lane = tid & 63, quad = lane >> 4, l16 = lane & 15;
    int wr = wave >> 1, wc = wave & 1;
    int bm = blockIdx.y * 128, bn = blockIdx.x * 128;

    f32x4 acc[4][4];
#pragma unroll
    for (int m = 0; m < 4; ++m)
#pragma unroll
        for (int n = 0; n < 4; ++n) acc[m][n] = (f32x4){0.f, 0.f, 0.f, 0.f};

    int srow = tid >> 2;            // 0..63: staged row within half-tile
    int sk = (tid & 3) * 8;         // k-element chunk (8 bf16 = 16 B)
    const ushort_t* Bt0 = &BT[(size_t)(bn + srow) * K + sk];
    const ushort_t* Bt1 = &BT[(size_t)(bn + 64 + srow) * K + sk];
    char* AlsDst = (char*)&Als[0][0] + tid * 16;
    char* BlsDst = (char*)&Bls[0][0] + tid * 16;
    const ushort_t* At0 = nullptr;
    const ushort_t* At1 = nullptr;
    if constexpr (!AF32) {
        const ushort_t* A = (const ushort_t*)Aptr;
        At0 = &A[(size_t)(bm + srow) * K + sk];
        At1 = &A[(size_t)(bm + 64 + srow) * K + sk];
    }

#pragma unroll 1
    for (int k0 = 0; k0 < K; k0 += 32) {
        if constexpr (AF32) {
            const float* A = (const float*)Aptr;
#pragma unroll
            for (int j = 0; j < 4; ++j) {
                int f = tid + 256 * j;          // float4 id in [128][32] tile
                int r = f >> 3, c4 = f & 7;
                float4 av =
                    *(const float4*)&A[(size_t)(bm + r) * K + k0 + c4 * 4];
                u32x2 w;
                w[0] = cvt_pk_bf16(av.x, av.y);
                w[1] = cvt_pk_bf16(av.z, av.w);
                *(u32x2*)&Als[r][c4 * 4] = w;
            }
        } else {
            gload16(At0 + k0, AlsDst);
            gload16(At1 + k0, AlsDst + 4096);
        }
        gload16(Bt0 + k0, BlsDst);
        gload16(Bt1 + k0, BlsDst + 4096);
        __syncthreads();   // waits vmcnt(0): global_load_lds done

        bf16x8 af[4], bfr[4];
#pragma unroll
        for (int m = 0; m < 4; ++m)
            af[m] = *(const bf16x8*)&Als[wr * 64 + m * 16 + l16][quad * 8];
#pragma unroll
        for (int n = 0; n < 4; ++n)
            bfr[n] = *(const bf16x8*)&Bls[wc * 64 + n * 16 + l16][quad * 8];
#pragma unroll
        for (int m = 0; m < 4; ++m)
#pragma unroll
            for (int n = 0; n < 4; ++n)
                acc[m][n] = __builtin_amdgcn_mfma_f32_16x16x32_bf16(
                    af[m], bfr[n], acc[m][n], 0, 0, 0);
        __syncthreads();
    }

    // C/D frag mapping: col = l16, row = quad*4 + i
    int rbase = bm + wr * 64 + quad * 4;
    if constexpr (EPI == 0 || EPI == 1) {
#pragma unroll
        for (int n = 0; n < 4; ++n) {
            int col = bn + wc * 64 + n * 16 + l16;
            float bv = bias[col];
#pragma unroll
            for (int m = 0; m < 4; ++m) {
#pragma unroll
                for (int i = 0; i < 4; ++i) {
                    float v = acc[m][n][i] + bv;
                    if constexpr (EPI == 0) v = fmaxf(v, 0.f);
                    Cout[(size_t)(rbase + m * 16 + i) * ldc + col] = f2bf(v);
                }
            }
        }
    } else {
        float s[4][4];
#pragma unroll
        for (int m = 0; m < 4; ++m)
#pragma unroll
            for (int i = 0; i < 4; ++i) s[m][i] = 0.f;
#pragma unroll
        for (int n = 0; n < 4; ++n) {
            int col = bn + wc * 64 + n * 16 + l16;
            float bv = bias[col], w2 = wc2[col];
#pragma unroll
            for (int m = 0; m < 4; ++m)
#pragma unroll
                for (int i = 0; i < 4; ++i)
                    s[m][i] += fmaxf(acc[m][n][i] + bv, 0.f) * w2;
        }
#pragma unroll
        for (int m = 0; m < 4; ++m)
#pragma unroll
            for (int i = 0; i < 4; ++i) {
                float v = s[m][i];
                v += __shfl_xor(v, 1);
                v += __shfl_xor(v, 2);
                v += __shfl_xor(v, 4);
                v += __shfl_xor(v, 8);
                if (l16 == 0) atomicAdd(&value[rbase + m * 16 + i], v);
            }
    }
}

// ---------------- rowwise LayerNorm over H=512, in-place on bf16 --------
__global__ __launch_bounds__(256) void ln_kernel(ushort_t* __restrict__ emb,
                                                 const float* __restrict__ scale,
                                                 const float* __restrict__ biasv) {
    int wave = threadIdx.x >> 6, lane = threadIdx.x & 63;
    size_t row = (size_t)blockIdx.x * 4 + wave;
    ushort_t* p = &emb[row * HD + lane * 8];
    bf16x8 xv = *(const bf16x8*)p;
    float x[8];
    float sum = 0.f, sq = 0.f;
    for (int j = 0; j < 8; ++j) {
        x[j] = bf2f((ushort_t)xv[j]);
        sum += x[j];
        sq += x[j] * x[j];
    }
    for (int off = 32; off > 0; off >>= 1) {
        sum += __shfl_xor(sum, off);
        sq += __shfl_xor(sq, off);
    }
    float mean = sum * (1.f / 512.f);
    float var = fmaxf(sq * (1.f / 512.f) - mean * mean, 0.f);
    float inv = rsqrtf(var + 1e-6f);
    bf16x8 ov;
    for (int j = 0; j < 8; ++j) {
        int col = lane * 8 + j;
        ov[j] = (short)f2bf((x[j] - mean) * inv * scale[col] + biasv[col]);
    }
    *(bf16x8*)p = ov;
}

// ---------------- GRU scan: per-wave decoupled, Wh in registers --------
// 256 blocks x 4 waves. bg = bid&7 (XCD-local under bid%8 heuristic —
// perf only), cg = bid>>3. Wave w of block (bg,cg) owns rows
// [bg*64+w*16,+16) x cols [cg*16,+16). Dependency is exactly per-(bg,w):
// wave w reads h rows produced by wave w of the 32 blocks (bg,*).
// Sync: flag word per (bg,w,cg) in bar; producer does {publish h stores
// (sc0 sc1), s_waitcnt vmcnt(0), flag <- t+2}; consumers poll all 32
// flags with one wave-wide load + ballot. NO __syncthreads in the loop,
// no LDS: Wh fragments live in registers (48 x bf16x8 = 192 VGPR; at 1
// block/CU each wave has a full SIMD register budget, bounds (256,1)).
// ys stores + xproj prefetch issued AFTER the flag store so they overlap
// the next step's poll instead of serializing before the arrive.
__global__ __launch_bounds__(256, 1) void scan_coop(
    const float* __restrict__ hidden, const int* __restrict__ dones,
    const ushort_t* __restrict__ WhT, const float* __restrict__ bhn,
    const ushort_t* __restrict__ xproj, ushort_t* __restrict__ ys,
    float* __restrict__ hlast, ushort_t* hb0, ushort_t* hb1,
    unsigned* bar) {
    int tid = threadIdx.x;
    int wave = tid >> 6, lane = tid & 63, quad = lane >> 4, l16 = lane & 15;
    int bid = blockIdx.x;
    int bg = bid & 7, cg = bid >> 3;
    int row0 = bg * 64 + wave * 16;   // this wave's 16 batch rows
    int col0 = cg * 16;               // this block's 16 h-cols

    // ---- Wh fragments -> registers (time-invariant; 192 VGPRs) ----
    // wR[kt] multiplies h k-chunk kt for output col (col0+l16):
    //   WhT[(gate*512 + col0 + l16)*512 + kt*32 + quad*8]
    bf16x8 wR[16], wZ[16], wN[16];
    {
        const ushort_t* w0 = &WhT[(size_t)(col0 + l16) * 512 + quad * 8];
#pragma unroll
        for (int kt = 0; kt < 16; ++kt) {
            wR[kt] = *(const bf16x8*)&w0[kt * 32];
            wZ[kt] = *(const bf16x8*)&w0[262144 + kt * 32];
            wN[kt] = *(const bf16x8*)&w0[524288 + kt * 32];
        }
    }

    // ---- fp32 master h (C-layout: col=l16, row=quad*4+i), done(0)-masked --
    float mast[4];
    int rbase = row0 + quad * 4;
#pragma unroll
    for (int i = 0; i < 4; ++i) {
        float h0 = hidden[(size_t)(rbase + i) * HD + col0 + l16];
        mast[i] = dones[rbase + i] ? 0.f : h0;   // dones[0*BATCH + r]
    }
    float bhnv = bhn[col0 + l16];

    // per-(bg,wave) flag row: 32 words, one per cg
    unsigned* flg = &bar[(unsigned)((bg * 4 + wave) * 32)];

    // ---- publish(0) into hb0 ----
#pragma unroll
    for (int i = 0; i < 4; ++i) {
        unsigned u = f2bf(mast[i]);
        unsigned p1 = __shfl_xor((int)u, 1);
        unsigned u32 = u | (p1 << 16);
        unsigned hi = __shfl_xor((int)u32, 2);
        if ((l16 & 3) == 0) {
            unsigned long long q =
                (unsigned long long)u32 | ((unsigned long long)hi << 32);
            __hip_atomic_store(
                (unsigned long long*)&hb0[(size_t)(rbase + i) * HD + col0 + l16],
                q, __ATOMIC_RELAXED, __HIP_MEMORY_SCOPE_AGENT);
        }
    }
    asm volatile("s_waitcnt vmcnt(0)" ::: "memory");   // h(0) visible
    if (lane == 0)
        __hip_atomic_store(&flg[cg], 1u, __ATOMIC_RELAXED,
                           __HIP_MEMORY_SCOPE_AGENT);
    // prefetch xproj(0) and dones(1) — overlaps first poll
    float xr[4], xz[4], xn[4];
    int dn_nxt[4];
#pragma unroll
    for (int i = 0; i < 4; ++i) {
        size_t m = (size_t)(rbase + i);
        const ushort_t* xp = &xproj[m * 1536 + col0 + l16];
        xr[i] = bf2f(xp[0]);
        xz[i] = bf2f(xp[512]);
        xn[i] = bf2f(xp[1024]);
        dn_nxt[i] = dones[BATCH + rbase + i];
    }
    asm volatile("" ::: "memory");

    for (int t = 0; t < T_STEPS; ++t) {
        // ---- per-wave barrier: all 32 producer waves published h(t) ----
        {
            unsigned tgt = (unsigned)(t + 1);
            for (;;) {
                unsigned f = __hip_atomic_load(&flg[lane & 31], __ATOMIC_RELAXED,
                                               __HIP_MEMORY_SCOPE_AGENT);
                if (__ballot(f >= tgt) == ~0ull) break;
                __builtin_amdgcn_s_sleep(1);
            }
        }
        asm volatile("" ::: "memory");
        ushort_t* rbuf = (t & 1) ? hb1 : hb0;
        ushort_t* wnext = (t & 1) ? hb0 : hb1;

        // ---- a-frags: one asm batch, 16 independent 16B sc0+sc1 loads,
        //      single waitcnt inside the block (no compiler serialization)
        bf16x8 afr[16];
        {
            const ushort_t* ap =
                &rbuf[(size_t)(row0 + l16) * HD + quad * 8];
            asm volatile(
                "global_load_dwordx4 %0, %16, off sc0 sc1\n\t"
                "global_load_dwordx4 %1, %16, off offset:64 sc0 sc1\n\t"
                "global_load_dwordx4 %2, %16, off offset:128 sc0 sc1\n\t"
                "global_load_dwordx4 %3, %16, off offset:192 sc0 sc1\n\t"
                "global_load_dwordx4 %4, %16, off offset:256 sc0 sc1\n\t"
                "global_load_dwordx4 %5, %16, off offset:320 sc0 sc1\n\t"
                "global_load_dwordx4 %6, %16, off offset:384 sc0 sc1\n\t"
                "global_load_dwordx4 %7, %16, off offset:448 sc0 sc1\n\t"
                "global_load_dwordx4 %8, %16, off offset:512 sc0 sc1\n\t"
                "global_load_dwordx4 %9, %16, off offset:576 sc0 sc1\n\t"
                "global_load_dwordx4 %10, %16, off offset:640 sc0 sc1\n\t"
                "global_load_dwordx4 %11, %16, off offset:704 sc0 sc1\n\t"
                "global_load_dwordx4 %12, %16, off offset:768 sc0 sc1\n\t"
                "global_load_dwordx4 %13, %16, off offset:832 sc0 sc1\n\t"
                "global_load_dwordx4 %14, %16, off offset:896 sc0 sc1\n\t"
                "global_load_dwordx4 %15, %16, off offset:960 sc0 sc1\n\t"
                "s_waitcnt vmcnt(0)"
                : "=&v"(afr[0]), "=&v"(afr[1]), "=&v"(afr[2]), "=&v"(afr[3]),
                  "=&v"(afr[4]), "=&v"(afr[5]), "=&v"(afr[6]), "=&v"(afr[7]),
                  "=&v"(afr[8]), "=&v"(afr[9]), "=&v"(afr[10]), "=&v"(afr[11]),
                  "=&v"(afr[12]), "=&v"(afr[13]), "=&v"(afr[14]), "=&v"(afr[15])
                : "v"(ap)
                : "memory");
        }
        f32x4 aR = (f32x4){0.f, 0.f, 0.f, 0.f};
        f32x4 aZ = (f32x4){0.f, 0.f, 0.f, 0.f};
        f32x4 aN = (f32x4){0.f, 0.f, 0.f, 0.f};
#pragma unroll
        for (int kt = 0; kt < 16; ++kt) {
            aR = __builtin_amdgcn_mfma_f32_16x16x32_bf16(afr[kt], wR[kt], aR, 0, 0, 0);
            aZ = __builtin_amdgcn_mfma_f32_16x16x32_bf16(afr[kt], wZ[kt], aZ, 0, 0, 0);
            aN = __builtin_amdgcn_mfma_f32_16x16x32_bf16(afr[kt], wN[kt], aN, 0, 0, 0);
        }

        // ---- gates; pack hnew 4 lanes->8B once, reuse for publish & ys ----
        unsigned long long qpk[4];
        float hnew[4];
#pragma unroll
        for (int i = 0; i < 4; ++i) {
            float r = fsigmoid(xr[i] + aR[i]);
            float z = fsigmoid(xz[i] + aZ[i]);
            float n = ftanh(xn[i] + r * (aN[i] + bhnv));
            hnew[i] = (1.f - z) * n + z * mast[i];
            unsigned u = f2bf(hnew[i]);
            unsigned p1 = __shfl_xor((int)u, 1);
            unsigned u32 = u | (p1 << 16);
            unsigned hi = __shfl_xor((int)u32, 2);
            qpk[i] = (unsigned long long)u32 | ((unsigned long long)hi << 32);
            mast[i] = (t < T_STEPS - 1 && dn_nxt[i]) ? 0.f : hnew[i];
        }
        if (t < T_STEPS - 1 && (l16 & 3) == 0) {
#pragma unroll
            for (int i = 0; i < 4; ++i) {
                unsigned long long qp = dn_nxt[i] ? 0ull : qpk[i];
                __hip_atomic_store(
                    (unsigned long long*)&wnext[(size_t)(rbase + i) * HD +
                                                col0 + l16],
                    qp, __ATOMIC_RELAXED, __HIP_MEMORY_SCOPE_AGENT);
            }
        }
        asm volatile("s_waitcnt vmcnt(0)" ::: "memory");   // h(t+1) visible
        if (t < T_STEPS - 1 && lane == 0)
            __hip_atomic_store(&flg[cg], (unsigned)(t + 2), __ATOMIC_RELAXED,
                               __HIP_MEMORY_SCOPE_AGENT);
        asm volatile("" ::: "memory");
        // ---- ys stores (packed 8B) + next-step prefetch: overlap poll ----
        if ((l16 & 3) == 0) {
#pragma unroll
            for (int i = 0; i < 4; ++i) {
                size_t m = (size_t)t * BATCH + rbase + i;
                *(unsigned long long*)&ys[m * HD + col0 + l16] = qpk[i];
            }
        }
        if (t < T_STEPS - 1) {
            int tn = t + 1;
            int td = (t + 2 < T_STEPS) ? t + 2 : T_STEPS - 1;
#pragma unroll
            for (int i = 0; i < 4; ++i) {
                size_t m = (size_t)tn * BATCH + rbase + i;
                const ushort_t* xp = &xproj[m * 1536 + col0 + l16];
                xr[i] = bf2f(xp[0]);
                xz[i] = bf2f(xp[512]);
                xn[i] = bf2f(xp[1024]);
                dn_nxt[i] = dones[td * BATCH + rbase + i];
            }
        }
        asm volatile("" ::: "memory");   // pin prefetch above next poll
    }
#pragma unroll
    for (int i = 0; i < 4; ++i)
        hlast[(size_t)(rbase + i) * HD + col0 + l16] = mast[i];
}

extern "C" void kernel_launch(void* const* d_in, const int* in_sizes, int n_in,
                              void* d_out, int out_size, void* d_ws,
                              size_t ws_size, hipStream_t stream) {
    const float* hidden      = (const float*)d_in[0];
    const float* world_state = (const float*)d_in[1];
    const int*   dones       = (const int*)d_in[2];
    const float* Wd  = (const float*)d_in[3];
    const float* bd  = (const float*)d_in[4];
    const float* lns = (const float*)d_in[5];
    const float* lnb = (const float*)d_in[6];
    const float* Wi  = (const float*)d_in[7];
    const float* bi  = (const float*)d_in[8];
    const float* Wh  = (const float*)d_in[9];
    const float* bhn = (const float*)d_in[10];
    const float* Wc1 = (const float*)d_in[11];
    const float* bc1 = (const float*)d_in[12];
    const float* Wc2 = (const float*)d_in[13];
    const float* bc2 = (const float*)d_in[14];

    float* out_h = (float*)d_out;            // h_last [512,512]
    float* out_v = out_h + BATCH * HD;       // value  [128,512]

    char* ws = (char*)d_ws;
    ushort_t* WdT   = (ushort_t*)(ws + 0);            // [512][1024]
    ushort_t* WiT   = (ushort_t*)(ws + 1048576);      // [1536][512]
    ushort_t* WhT   = (ushort_t*)(ws + 2621440);      // [1536][512]
    ushort_t* Wc1T  = (ushort_t*)(ws + 4194304);      // [512][512]
    unsigned* bar   = (unsigned*)(ws + 4718592);      // 2048 uints (8 KB)
    ushort_t* hb0   = (ushort_t*)(ws + 4726784);      // [512][512] bf16
    ushort_t* hb1   = (ushort_t*)(ws + 5251072);      // [512][512] bf16
    ushort_t* xproj = (ushort_t*)(ws + 8388608);      // [65536][1536] bf16
    ushort_t* emb   = (ushort_t*)(ws + 209715200);    // [65536][512] bf16
    ushort_t* ysb   = emb;  // reuse: emb dead after gemm2, ys written by scan

    dim3 tb(32, 8);
    transpose_to_bf16<<<dim3(16, 32), tb, 0, stream>>>(Wd, WdT, OBSD, HD);
    transpose_to_bf16<<<dim3(48, 16), tb, 0, stream>>>(Wi, WiT, HD, 1536);
    transpose_to_bf16<<<dim3(48, 16), tb, 0, stream>>>(Wh, WhT, HD, 1536);
    transpose_to_bf16<<<dim3(16, 16), tb, 0, stream>>>(Wc1, Wc1T, HD, FCD);
    init_misc<<<256, 256, 0, stream>>>(out_v, bc2, bar);

    // emb = relu(world_state @ Wd + bd)   (fp32 A reg-staged w/ cvt_pk)
    gemm128<OBSD, 0, true><<<dim3(HD / 128, MROWS / 128), 256, 0, stream>>>(
        world_state, WdT, bd, emb, HD, nullptr, nullptr);
    // LayerNorm in place
    ln_kernel<<<MROWS / 4, 256, 0, stream>>>(emb, lns, lnb);
    // xproj = emb @ Wi + bi
    gemm128<HD, 1, false><<<dim3(1536 / 128, MROWS / 128), 256, 0, stream>>>(
        emb, WiT, bi, xproj, 1536, nullptr, nullptr);
    // persistent GRU scan: 256 blocks, per-wave flag sync, Wh in registers
    scan_coop<<<dim3(256), dim3(256), 0, stream>>>(
        hidden, dones, WhT, bhn, xproj, ysb, out_h, hb0, hb1, bar);
    // value = relu(ys @ Wc1 + bc1) @ Wc2 + bc2
    gemm128<HD, 2, false><<<dim3(FCD / 128, MROWS / 128), 256, 0, stream>>>(
        ysb, Wc1T, bc1, nullptr, 0, Wc2, out_v);
}